// Round 1
// baseline (230.239 us; speedup 1.0000x reference)
//
#include <hip/hip_runtime.h>

// DrQv2 random-shift augmentation.
// out[b,c,i,j] = x[b,c, clamp(i+sy-4,0,H-1), clamp(j+sx-4,0,W-1)]
// Pure memory-bound gather: 130 MB in + 130 MB out.

#define PAD 4

constexpr int NIMG  = 512;          // B*L = 32*16
constexpr int C     = 9;
constexpr int H     = 84;
constexpr int W     = 84;
constexpr int PLANE = H * W;        // 7056
constexpr int IMG   = C * PLANE;    // 63504
constexpr int TOTAL = NIMG * IMG;   // 32514048
constexpr int TOTAL4 = TOTAL / 4;   // 8128512 (W % 4 == 0, so a float4 stays in one row)

__global__ __launch_bounds__(256)
void drq_aug_kernel(const float* __restrict__ x,
                    const int*   __restrict__ shift,
                    float*       __restrict__ out)
{
    const int stride = gridDim.x * blockDim.x;
    for (int t = blockIdx.x * blockDim.x + threadIdx.x; t < TOTAL4; t += stride) {
        const int idx  = t << 2;              // flat element index of first lane of the float4
        const int b    = idx / IMG;
        const int rem  = idx - b * IMG;
        const int c    = rem / PLANE;
        const int rem2 = rem - c * PLANE;
        const int i    = rem2 / W;
        const int j    = rem2 - i * W;        // multiple of 4

        const int2 s  = ((const int2*)shift)[b];   // s.x = sx, s.y = sy
        int si = i + s.y - PAD;
        si = si < 0 ? 0 : (si > H - 1 ? H - 1 : si);

        const float* __restrict__ row = x + (size_t)b * IMG + c * PLANE + si * W;

        const int j0 = j + s.x - PAD;
        float4 v;
        {
            int ja = j0;     ja = ja < 0 ? 0 : (ja > W - 1 ? W - 1 : ja);
            int jb = j0 + 1; jb = jb < 0 ? 0 : (jb > W - 1 ? W - 1 : jb);
            int jc = j0 + 2; jc = jc < 0 ? 0 : (jc > W - 1 ? W - 1 : jc);
            int jd = j0 + 3; jd = jd < 0 ? 0 : (jd > W - 1 ? W - 1 : jd);
            v.x = row[ja];
            v.y = row[jb];
            v.z = row[jc];
            v.w = row[jd];
        }
        ((float4*)out)[t] = v;
    }
}

extern "C" void kernel_launch(void* const* d_in, const int* in_sizes, int n_in,
                              void* d_out, int out_size, void* d_ws, size_t ws_size,
                              hipStream_t stream)
{
    const float* x     = (const float*)d_in[0];
    const int*   shift = (const int*)d_in[1];
    float*       out   = (float*)d_out;

    const int block = 256;
    const int grid  = 2048;   // grid-stride; ~15.5 float4 per thread
    drq_aug_kernel<<<grid, block, 0, stream>>>(x, shift, out);
}

// Round 2
// 226.694 us; speedup vs baseline: 1.0156x; 1.0156x over previous
//
#include <hip/hip_runtime.h>

// DrQv2 random-shift augmentation.
// out[b,c,i,j] = x[b,c, clamp(i+sy-4,0,H-1), clamp(j+sx-4,0,W-1)]
// One block per (b,c) plane: shift is block-uniform (scalar load), and each
// thread's 7 float4 outputs are unrolled so ~24 loads are in flight per wave.

#define PAD 4

constexpr int NIMG   = 512;          // B*L
constexpr int C      = 9;
constexpr int H      = 84;
constexpr int W      = 84;
constexpr int PLANE  = H * W;        // 7056 floats per plane
constexpr int PLANE4 = PLANE / 4;    // 1764 float4 per plane
constexpr int W4     = W / 4;        // 21 float4 per row

__device__ __forceinline__ void do_one(const float* __restrict__ src,
                                       float* __restrict__ dst,
                                       int p, int dx, int dy)
{
    int i  = p / W4;                  // output row
    int j4 = p - i * W4;              // float4 index within row
    int si = i + dy;
    si = si < 0 ? 0 : (si > H - 1 ? H - 1 : si);
    const float* __restrict__ row = src + si * W;

    int j0 = (j4 << 2) + dx;
    int ja = j0;     ja = ja < 0 ? 0 : (ja > W - 1 ? W - 1 : ja);
    int jb = j0 + 1; jb = jb < 0 ? 0 : (jb > W - 1 ? W - 1 : jb);
    int jc = j0 + 2; jc = jc < 0 ? 0 : (jc > W - 1 ? W - 1 : jc);
    int jd = j0 + 3; jd = jd < 0 ? 0 : (jd > W - 1 ? W - 1 : jd);

    float4 v = make_float4(row[ja], row[jb], row[jc], row[jd]);
    ((float4*)dst)[p] = v;
}

__global__ __launch_bounds__(256)
void drq_aug_kernel(const float* __restrict__ x,
                    const int*   __restrict__ shift,
                    float*       __restrict__ out)
{
    const int blk = blockIdx.x;            // blk = b*C + c
    const int b   = blk / C;
    // Uniform per block -> scalar loads, no per-thread dependent gather.
    const int dx  = shift[2 * b]     - PAD;
    const int dy  = shift[2 * b + 1] - PAD;

    // b*IMG + c*PLANE == blk*PLANE
    const float* __restrict__ src = x   + (size_t)blk * PLANE;
    float*       __restrict__ dst = out + (size_t)blk * PLANE;

    const int tid = threadIdx.x;

    // 6 full rounds, unconditional -> 24 independent loads in flight.
    #pragma unroll
    for (int r = 0; r < 6; ++r) {
        do_one(src, dst, r * 256 + tid, dx, dy);
    }
    // Tail round: 1764 - 6*256 = 228 active threads.
    {
        int p = 6 * 256 + tid;
        if (p < PLANE4) do_one(src, dst, p, dx, dy);
    }
}

extern "C" void kernel_launch(void* const* d_in, const int* in_sizes, int n_in,
                              void* d_out, int out_size, void* d_ws, size_t ws_size,
                              hipStream_t stream)
{
    const float* x     = (const float*)d_in[0];
    const int*   shift = (const int*)d_in[1];
    float*       out   = (float*)d_out;

    const int grid = NIMG * C;   // 4608 blocks, one per plane
    drq_aug_kernel<<<grid, 256, 0, stream>>>(x, shift, out);
}